// Round 1
// baseline (1286.296 us; speedup 1.0000x reference)
//
#include <hip/hip_runtime.h>
#include <math.h>

#define T_SEQ 1024
#define FEAT  512
#define NH    8
#define DKH   64

// ---------------------------------------------------------------------------
// GEMM: C[M,N] = A[M,K] @ W[N,K]^T + bias   (fp32, 64x64 tile, 4x4 micro)
// ---------------------------------------------------------------------------
#define GK  16
#define GST 68   // LDS row stride (floats); 68 % 32 == 4 -> 2-way worst case

__global__ __launch_bounds__(256)
void gemm_bias(const float* __restrict__ A, const float* __restrict__ W,
               const float* __restrict__ bias, float* __restrict__ C,
               int M, int N, int K)
{
    __shared__ float As[GK][GST];
    __shared__ float Bs[GK][GST];
    const int tid = threadIdx.x;
    const int tx = tid & 15, ty = tid >> 4;
    const int m0 = blockIdx.x * 64, n0 = blockIdx.y * 64;
    const int lr = tid >> 2, lk = tid & 3;

    float acc[4][4] = {{0.f,0.f,0.f,0.f},{0.f,0.f,0.f,0.f},
                       {0.f,0.f,0.f,0.f},{0.f,0.f,0.f,0.f}};

    const int arow = m0 + lr;
    const int brow = n0 + lr;
    float4 areg = make_float4(0.f,0.f,0.f,0.f);
    float4 breg;
    if (arow < M) areg = *(const float4*)&A[(size_t)arow * K + lk*4];
    breg = *(const float4*)&W[(size_t)brow * K + lk*4];

    const int nch = K / GK;
    for (int kc = 0; kc < nch; ++kc) {
        __syncthreads();
        As[lk*4+0][lr] = areg.x; As[lk*4+1][lr] = areg.y;
        As[lk*4+2][lr] = areg.z; As[lk*4+3][lr] = areg.w;
        Bs[lk*4+0][lr] = breg.x; Bs[lk*4+1][lr] = breg.y;
        Bs[lk*4+2][lr] = breg.z; Bs[lk*4+3][lr] = breg.w;
        __syncthreads();
        if (kc + 1 < nch) {
            const int k0 = (kc + 1) * GK;
            if (arow < M) areg = *(const float4*)&A[(size_t)arow * K + k0 + lk*4];
            breg = *(const float4*)&W[(size_t)brow * K + k0 + lk*4];
        }
#pragma unroll
        for (int kk = 0; kk < GK; ++kk) {
            const float4 a = *(const float4*)&As[kk][4*ty];
            const float4 b = *(const float4*)&Bs[kk][4*tx];
            acc[0][0] += a.x*b.x; acc[0][1] += a.x*b.y; acc[0][2] += a.x*b.z; acc[0][3] += a.x*b.w;
            acc[1][0] += a.y*b.x; acc[1][1] += a.y*b.y; acc[1][2] += a.y*b.z; acc[1][3] += a.y*b.w;
            acc[2][0] += a.z*b.x; acc[2][1] += a.z*b.y; acc[2][2] += a.z*b.z; acc[2][3] += a.z*b.w;
            acc[3][0] += a.w*b.x; acc[3][1] += a.w*b.y; acc[3][2] += a.w*b.z; acc[3][3] += a.w*b.w;
        }
    }

    float4 bv = make_float4(0.f,0.f,0.f,0.f);
    if (bias) bv = *(const float4*)&bias[n0 + 4*tx];
#pragma unroll
    for (int i = 0; i < 4; ++i) {
        const int row = m0 + 4*ty + i;
        if (row < M) {
            float4 o;
            o.x = acc[i][0] + bv.x; o.y = acc[i][1] + bv.y;
            o.z = acc[i][2] + bv.z; o.w = acc[i][3] + bv.w;
            *(float4*)&C[(size_t)row * N + n0 + 4*tx] = o;
        }
    }
}

// ---------------------------------------------------------------------------
// Relative-position flash attention.
// Block: 64 q-rows of one (b,h). 256 threads (16x16), 4x4 micro-tiles.
// bd[t,s] = q_v[t] . p[(T-1) - t + s]  (rel_shift folded into index)
// ---------------------------------------------------------------------------
#define AST  68    // stride for qu/qv/kt/vt/pt tiles
#define BDST 133   // stride for bd; 133 -> shifted read is ~2-way

__global__ __launch_bounds__(256)
void attn_rel(const float* __restrict__ qb, const float* __restrict__ kb,
              const float* __restrict__ vb, const float* __restrict__ pb,
              const int* __restrict__ mask,
              const float* __restrict__ pbu, const float* __restrict__ pbv,
              float* __restrict__ xout)
{
    extern __shared__ float sm[];
    float* qu = sm;               // [64][AST]
    float* qv = qu + 64*AST;      // [64][AST]
    float* kt = qv + 64*AST;      // [64][AST]
    float* vt = kt + 64*AST;      // [64][AST]
    float* pt = vt + 64*AST;      // [128][AST] (row 127 zeroed; also reused for P)
    float* bd = pt + 128*AST;     // [64][BDST]

    const int tid = threadIdx.x;
    const int tx = tid & 15, ty = tid >> 4;
    const int t0 = blockIdx.x * 64;
    const int b  = blockIdx.y >> 3, h = blockIdx.y & 7;

    const float* qsrc = qb + (size_t)b*T_SEQ*FEAT + h*DKH;
    const float* ksrc = kb + (size_t)b*T_SEQ*FEAT + h*DKH;
    const float* vsrc = vb + (size_t)b*T_SEQ*FEAT + h*DKH;
    const float* psrc = pb + h*DKH;

    const float4 ub  = *(const float4*)&pbu[h*DKH + tx*4];
    const float4 vbs = *(const float4*)&pbv[h*DKH + tx*4];
#pragma unroll
    for (int it = 0; it < 4; ++it) {
        const int r = ty + it*16;
        const float4 q4 = *(const float4*)&qsrc[(size_t)(t0+r)*FEAT + tx*4];
        float4 t;
        t.x = q4.x + ub.x;  t.y = q4.y + ub.y;  t.z = q4.z + ub.z;  t.w = q4.w + ub.w;
        *(float4*)&qu[r*AST + tx*4] = t;
        t.x = q4.x + vbs.x; t.y = q4.y + vbs.y; t.z = q4.z + vbs.z; t.w = q4.w + vbs.w;
        *(float4*)&qv[r*AST + tx*4] = t;
    }

    float m_r[4], l_r[4], acc[4][4];
#pragma unroll
    for (int i = 0; i < 4; ++i) {
        m_r[i] = -3.0e38f; l_r[i] = 0.f;
#pragma unroll
        for (int j = 0; j < 4; ++j) acc[i][j] = 0.f;
    }

    for (int st = 0; st < 16; ++st) {
        const int s0 = st * 64;
        const int base = (T_SEQ - DKH) - t0 + s0;   // 960 - t0 + s0; p row = base + (63 - ti + si)
        __syncthreads();   // bar A: prev iteration readers done
#pragma unroll
        for (int it = 0; it < 4; ++it) {
            const int r = ty + it*16;
            *(float4*)&kt[r*AST + tx*4] = *(const float4*)&ksrc[(size_t)(s0+r)*FEAT + tx*4];
            *(float4*)&vt[r*AST + tx*4] = *(const float4*)&vsrc[(size_t)(s0+r)*FEAT + tx*4];
        }
#pragma unroll
        for (int it = 0; it < 8; ++it) {
            const int r = ty + it*16;
            float4 p4 = make_float4(0.f,0.f,0.f,0.f);
            if (r < 127) p4 = *(const float4*)&psrc[(size_t)(base+r)*FEAT + tx*4];
            *(float4*)&pt[r*AST + tx*4] = p4;
        }
        __syncthreads();   // bar B: tiles ready

        // ---- AC: (q+u) . k^T  -> registers; cols si = tx + 16j
        float sac[4][4] = {{0.f,0.f,0.f,0.f},{0.f,0.f,0.f,0.f},
                           {0.f,0.f,0.f,0.f},{0.f,0.f,0.f,0.f}};
#pragma unroll
        for (int d4 = 0; d4 < 16; ++d4) {
            float4 a[4], kk[4];
#pragma unroll
            for (int i = 0; i < 4; ++i) a[i] = *(const float4*)&qu[(4*ty+i)*AST + d4*4];
#pragma unroll
            for (int j = 0; j < 4; ++j) kk[j] = *(const float4*)&kt[(tx+16*j)*AST + d4*4];
#pragma unroll
            for (int i = 0; i < 4; ++i) {
#pragma unroll
                for (int j = 0; j < 4; ++j)
                    sac[i][j] += a[i].x*kk[j].x + a[i].y*kk[j].y
                               + a[i].z*kk[j].z + a[i].w*kk[j].w;
            }
        }

        // ---- BD GEMM: (q+v) . p_window^T -> bd LDS [64][128 cols], col pr = tx+16jj
        float bda[4][8] = {{0.f,0.f,0.f,0.f,0.f,0.f,0.f,0.f},{0.f,0.f,0.f,0.f,0.f,0.f,0.f,0.f},
                           {0.f,0.f,0.f,0.f,0.f,0.f,0.f,0.f},{0.f,0.f,0.f,0.f,0.f,0.f,0.f,0.f}};
#pragma unroll
        for (int d4 = 0; d4 < 16; ++d4) {
            float4 a[4], pp[8];
#pragma unroll
            for (int i = 0; i < 4; ++i) a[i] = *(const float4*)&qv[(4*ty+i)*AST + d4*4];
#pragma unroll
            for (int jj = 0; jj < 8; ++jj) pp[jj] = *(const float4*)&pt[(tx+16*jj)*AST + d4*4];
#pragma unroll
            for (int i = 0; i < 4; ++i) {
#pragma unroll
                for (int jj = 0; jj < 8; ++jj)
                    bda[i][jj] += a[i].x*pp[jj].x + a[i].y*pp[jj].y
                                + a[i].z*pp[jj].z + a[i].w*pp[jj].w;
            }
        }
#pragma unroll
        for (int i = 0; i < 4; ++i)
#pragma unroll
            for (int jj = 0; jj < 8; ++jj)
                bd[(4*ty+i)*BDST + tx + 16*jj] = bda[i][jj];
        __syncthreads();   // bar C: bd visible; pt now free for P staging

        // ---- S assembly + online softmax (row groups = 16 contiguous lanes)
        int mk[4];
#pragma unroll
        for (int j = 0; j < 4; ++j) mk[j] = mask[b*T_SEQ + s0 + tx + 16*j];
#pragma unroll
        for (int i = 0; i < 4; ++i) {
            const int ti = 4*ty + i;
            float sv[4];
#pragma unroll
            for (int j = 0; j < 4; ++j) {
                const int si = tx + 16*j;
                const float vval = (sac[i][j] + bd[ti*BDST + 63 - ti + si]) * 0.125f;
                sv[j] = (mk[j] == 0) ? -1.0e30f : vval;
            }
            float mx = fmaxf(fmaxf(sv[0], sv[1]), fmaxf(sv[2], sv[3]));
            mx = fmaxf(mx, __shfl_xor(mx, 1, 16));
            mx = fmaxf(mx, __shfl_xor(mx, 2, 16));
            mx = fmaxf(mx, __shfl_xor(mx, 4, 16));
            mx = fmaxf(mx, __shfl_xor(mx, 8, 16));
            const float mnew = fmaxf(m_r[i], mx);
            const float corr = __expf(m_r[i] - mnew);
            m_r[i] = mnew;
            float rs = 0.f;
#pragma unroll
            for (int j = 0; j < 4; ++j) {
                const float e = (mk[j] == 0) ? 0.f : __expf(sv[j] - mnew);
                sv[j] = e; rs += e;
            }
            rs += __shfl_xor(rs, 1, 16); rs += __shfl_xor(rs, 2, 16);
            rs += __shfl_xor(rs, 4, 16); rs += __shfl_xor(rs, 8, 16);
            l_r[i] = l_r[i] * corr + rs;
#pragma unroll
            for (int j = 0; j < 4; ++j) acc[i][j] *= corr;
            // stage P into pt rows 0..63 (pt reads all completed before bar C)
#pragma unroll
            for (int j = 0; j < 4; ++j) pt[ti*AST + tx + 16*j] = sv[j];
        }
        __syncthreads();   // bar D: P visible

        // ---- PV: acc[i][j] += sum_s P[ti][s] * V[s][4tx+j]
#pragma unroll
        for (int s4 = 0; s4 < 16; ++s4) {
            float4 pa[4], vv[4];
#pragma unroll
            for (int i = 0; i < 4; ++i) pa[i] = *(const float4*)&pt[(4*ty+i)*AST + s4*4];
#pragma unroll
            for (int c = 0; c < 4; ++c) vv[c] = *(const float4*)&vt[(s4*4+c)*AST + tx*4];
#pragma unroll
            for (int i = 0; i < 4; ++i) {
                acc[i][0] += pa[i].x*vv[0].x + pa[i].y*vv[1].x + pa[i].z*vv[2].x + pa[i].w*vv[3].x;
                acc[i][1] += pa[i].x*vv[0].y + pa[i].y*vv[1].y + pa[i].z*vv[2].y + pa[i].w*vv[3].y;
                acc[i][2] += pa[i].x*vv[0].z + pa[i].y*vv[1].z + pa[i].z*vv[2].z + pa[i].w*vv[3].z;
                acc[i][3] += pa[i].x*vv[0].w + pa[i].y*vv[1].w + pa[i].z*vv[2].w + pa[i].w*vv[3].w;
            }
        }
    }

    // ---- epilogue: x[b, t, h*DK + dk] = acc / l
#pragma unroll
    for (int i = 0; i < 4; ++i) {
        const int row = t0 + 4*ty + i;
        const float inv = 1.0f / l_r[i];
        float4 o;
        o.x = acc[i][0]*inv; o.y = acc[i][1]*inv;
        o.z = acc[i][2]*inv; o.w = acc[i][3]*inv;
        *(float4*)&xout[((size_t)b*T_SEQ + row)*FEAT + h*DKH + tx*4] = o;
    }
}

// ---------------------------------------------------------------------------
extern "C" void kernel_launch(void* const* d_in, const int* in_sizes, int n_in,
                              void* d_out, int out_size, void* d_ws, size_t ws_size,
                              hipStream_t stream)
{
    (void)in_sizes; (void)n_in; (void)out_size; (void)ws_size;
    const float* query   = (const float*)d_in[0];
    const float* key_in  = (const float*)d_in[1];
    const float* value   = (const float*)d_in[2];
    const float* pos_emb = (const float*)d_in[3];
    const int*   mask    = (const int*)  d_in[4];
    const float* Wq = (const float*)d_in[5];
    const float* bq = (const float*)d_in[6];
    const float* Wk = (const float*)d_in[7];
    const float* bk = (const float*)d_in[8];
    const float* Wv = (const float*)d_in[9];
    const float* bv = (const float*)d_in[10];
    const float* Wo = (const float*)d_in[11];
    const float* bo = (const float*)d_in[12];
    const float* Wp = (const float*)d_in[13];
    const float* pbu = (const float*)d_in[14];
    const float* pbv = (const float*)d_in[15];
    float* out = (float*)d_out;

    const size_t NTOK = (size_t)8 * T_SEQ;        // 8192
    float* ws   = (float*)d_ws;
    float* qbuf = ws;
    float* kbuf = qbuf + NTOK * FEAT;
    float* vbuf = kbuf + NTOK * FEAT;
    float* xbuf = vbuf + NTOK * FEAT;
    float* pbuf = xbuf + NTOK * FEAT;             // 2047 x 512

    const dim3 blk(256);
    gemm_bias<<<dim3(128, 8), blk, 0, stream>>>(query,  Wq, bq, qbuf, 8192, FEAT, FEAT);
    gemm_bias<<<dim3(128, 8), blk, 0, stream>>>(key_in, Wk, bk, kbuf, 8192, FEAT, FEAT);
    gemm_bias<<<dim3(128, 8), blk, 0, stream>>>(value,  Wv, bv, vbuf, 8192, FEAT, FEAT);
    gemm_bias<<<dim3(32, 8),  blk, 0, stream>>>(pos_emb, Wp, nullptr, pbuf, 2047, FEAT, FEAT);

    const size_t lds_bytes = (size_t)(64*4 + 128) * AST * 4 + (size_t)64 * BDST * 4; // 138496
    hipFuncSetAttribute((const void*)attn_rel,
                        hipFuncAttributeMaxDynamicSharedMemorySize, (int)lds_bytes);
    attn_rel<<<dim3(16, 64), blk, lds_bytes, stream>>>(qbuf, kbuf, vbuf, pbuf,
                                                       mask, pbu, pbv, xbuf);

    gemm_bias<<<dim3(128, 8), blk, 0, stream>>>(xbuf, Wo, bo, out, 8192, FEAT, FEAT);
}

// Round 3
// 443.755 us; speedup vs baseline: 2.8987x; 2.8987x over previous
//
#include <hip/hip_runtime.h>
#include <math.h>

#define T_SEQ 1024
#define FEAT  512
#define NH    8
#define DKH   64

typedef __attribute__((ext_vector_type(8))) short          bf16x8;
typedef _Float16 f16;
typedef __attribute__((ext_vector_type(8))) _Float16       f16x8;
typedef __attribute__((ext_vector_type(4))) float          f32x4;
typedef __attribute__((ext_vector_type(8))) unsigned short u16x8;
typedef __attribute__((ext_vector_type(4))) unsigned short u16x4;

__device__ __forceinline__ float bf2f(unsigned short u) {
    union { unsigned int i; float f; } x; x.i = ((unsigned int)u) << 16; return x.f;
}
__device__ __forceinline__ unsigned short f2bf(float f) {
    union { float f; unsigned int i; } x; x.f = f;
    unsigned int r = x.i + 0x7FFFu + ((x.i >> 16) & 1u);
    return (unsigned short)(r >> 16);
}

// ---------------------------------------------------------------------------
// Pre-split the 5 weight matrices fp32 -> (hi, lo) bf16
// ---------------------------------------------------------------------------
struct WSplit {
    const float*    src[5];
    unsigned short* hi[5];
    unsigned short* lo[5];
};

__global__ __launch_bounds__(256)
void split_weights(WSplit pk) {
    const int ten = blockIdx.y;
    const float4* s = (const float4*)pk.src[ten];
    u16x4* dh = (u16x4*)pk.hi[ten];
    u16x4* dl = (u16x4*)pk.lo[ten];
    const int n4 = FEAT * FEAT / 4;
    for (int i = blockIdx.x * blockDim.x + threadIdx.x; i < n4;
         i += gridDim.x * blockDim.x) {
        const float4 v = s[i];
        float a[4] = {v.x, v.y, v.z, v.w};
        u16x4 h, l;
#pragma unroll
        for (int j = 0; j < 4; ++j) {
            h[j] = f2bf(a[j]);
            l[j] = f2bf(a[j] - bf2f(h[j]));
        }
        dh[i] = h; dl[i] = l;
    }
}

// ---------------------------------------------------------------------------
// Split-bf16 GEMM: C[M,N] = A[M,K] @ W[N,K]^T (+bias), fp32-accurate-ish
// A fp32 (split in-kernel), W pre-split hi/lo. 3 MFMAs per fragment pair.
// OUTMODE 0: fp32 C[M,N]; 1: fp16 C[M,N]; 2: fp16 V^T layout [b][col][t]
// ---------------------------------------------------------------------------
template<int OUTMODE>
__global__ __launch_bounds__(256)
void gemm_split(const float* __restrict__ A,
                const unsigned short* __restrict__ Wh,
                const unsigned short* __restrict__ Wl,
                const float* __restrict__ bias,
                void* __restrict__ Cout, int M, int N, int K)
{
    __shared__ unsigned short Ah[128][40];
    __shared__ unsigned short Al[128][40];
    __shared__ unsigned short Bh[128][40];
    __shared__ unsigned short Bl[128][40];

    const int tid  = threadIdx.x;
    const int w    = tid >> 6, lane = tid & 63, g = lane >> 4, c = lane & 15;
    const int m0   = blockIdx.x * 128, n0 = blockIdx.y * 128;
    const int wr   = (w >> 1) * 64, wc = (w & 1) * 64;
    const int r0   = tid >> 2, ch = tid & 3;

    f32x4 acc[4][4];
#pragma unroll
    for (int m = 0; m < 4; ++m)
#pragma unroll
        for (int n = 0; n < 4; ++n)
#pragma unroll
            for (int r = 0; r < 4; ++r) acc[m][n][r] = 0.f;

    float4 ar[2][2];
    u16x8  brh[2], brl[2];
    auto ldA = [&](int kc, int q, int half) -> float4 {
        const int gr = m0 + r0 + 64 * q;
        if (gr < M) return *(const float4*)&A[(size_t)gr * K + kc * 32 + ch * 8 + half * 4];
        return make_float4(0.f, 0.f, 0.f, 0.f);
    };
    auto ldBh = [&](int kc, int q) -> u16x8 {
        return *(const u16x8*)&Wh[(size_t)(n0 + r0 + 64 * q) * K + kc * 32 + ch * 8];
    };
    auto ldBl = [&](int kc, int q) -> u16x8 {
        return *(const u16x8*)&Wl[(size_t)(n0 + r0 + 64 * q) * K + kc * 32 + ch * 8];
    };
    auto storeA = [&](const float4& a0, const float4& a1, int row) {
        float v[8] = {a0.x, a0.y, a0.z, a0.w, a1.x, a1.y, a1.z, a1.w};
        u16x8 h, l;
#pragma unroll
        for (int j = 0; j < 8; ++j) {
            h[j] = f2bf(v[j]);
            l[j] = f2bf(v[j] - bf2f(h[j]));
        }
        *(u16x8*)&Ah[row][ch * 8] = h;
        *(u16x8*)&Al[row][ch * 8] = l;
    };

    ar[0][0] = ldA(0, 0, 0); ar[0][1] = ldA(0, 0, 1);
    ar[1][0] = ldA(0, 1, 0); ar[1][1] = ldA(0, 1, 1);
    brh[0] = ldBh(0, 0); brl[0] = ldBl(0, 0);
    brh[1] = ldBh(0, 1); brl[1] = ldBl(0, 1);

    const int nk = K / 32;
    for (int kc = 0; kc < nk; ++kc) {
        __syncthreads();
        storeA(ar[0][0], ar[0][1], r0);
        storeA(ar[1][0], ar[1][1], r0 + 64);
        *(u16x8*)&Bh[r0][ch * 8]      = brh[0];
        *(u16x8*)&Bl[r0][ch * 8]      = brl[0];
        *(u16x8*)&Bh[r0 + 64][ch * 8] = brh[1];
        *(u16x8*)&Bl[r0 + 64][ch * 8] = brl[1];
        __syncthreads();
        if (kc + 1 < nk) {
            ar[0][0] = ldA(kc + 1, 0, 0); ar[0][1] = ldA(kc + 1, 0, 1);
            ar[1][0] = ldA(kc + 1, 1, 0); ar[1][1] = ldA(kc + 1, 1, 1);
            brh[0] = ldBh(kc + 1, 0); brl[0] = ldBl(kc + 1, 0);
            brh[1] = ldBh(kc + 1, 1); brl[1] = ldBl(kc + 1, 1);
        }
        bf16x8 ah[4], al[4], bh[4], bl[4];
#pragma unroll
        for (int m = 0; m < 4; ++m) {
            ah[m] = *(const bf16x8*)&Ah[wr + 16 * m + c][8 * g];
            al[m] = *(const bf16x8*)&Al[wr + 16 * m + c][8 * g];
        }
#pragma unroll
        for (int n = 0; n < 4; ++n) {
            bh[n] = *(const bf16x8*)&Bh[wc + 16 * n + c][8 * g];
            bl[n] = *(const bf16x8*)&Bl[wc + 16 * n + c][8 * g];
        }
#pragma unroll
        for (int m = 0; m < 4; ++m)
#pragma unroll
            for (int n = 0; n < 4; ++n) {
                acc[m][n] = __builtin_amdgcn_mfma_f32_16x16x32_bf16(ah[m], bh[n], acc[m][n], 0, 0, 0);
                acc[m][n] = __builtin_amdgcn_mfma_f32_16x16x32_bf16(ah[m], bl[n], acc[m][n], 0, 0, 0);
                acc[m][n] = __builtin_amdgcn_mfma_f32_16x16x32_bf16(al[m], bh[n], acc[m][n], 0, 0, 0);
            }
    }

#pragma unroll
    for (int n = 0; n < 4; ++n) {
        const int gcol = n0 + wc + 16 * n + c;
        const float bb = bias ? bias[gcol] : 0.f;
#pragma unroll
        for (int m = 0; m < 4; ++m) {
            if (OUTMODE == 2) {
                const int grb = m0 + wr + 16 * m + 4 * g;
                const int bidx = grb >> 10, t = grb & 1023;
                u16x4 pk4;
#pragma unroll
                for (int r = 0; r < 4; ++r) {
                    const f16 hv = (f16)(acc[m][n][r] + bb);
                    pk4[r] = *(const unsigned short*)&hv;
                }
                *(u16x4*)&((unsigned short*)Cout)[((size_t)(bidx * FEAT + gcol)) * T_SEQ + t] = pk4;
            } else {
#pragma unroll
                for (int r = 0; r < 4; ++r) {
                    const int gr = m0 + wr + 16 * m + 4 * g + r;
                    if (gr < M) {
                        const float v = acc[m][n][r] + bb;
                        if (OUTMODE == 0) ((float*)Cout)[(size_t)gr * N + gcol] = v;
                        else              ((f16*)Cout)[(size_t)gr * N + gcol] = (f16)v;
                    }
                }
            }
        }
    }
}

// ---------------------------------------------------------------------------
// fp16-MFMA relative-position flash attention.
// 64 q-rows/block, 4 waves, 16x16x32 f16 MFMA, fp32 softmax/accum.
// bd[t,s] = q_v[t] . p[(T-1) - t + s]  (rel_shift folded into index)
// LDS (ushort units): qu,qv,kt,vtT 64x72; pt 128x72; ps 64x72; bdb 64x132
// total = 40704 ushort = 81408 B  -> 2 blocks/CU (2*81408 <= 163840)
// ---------------------------------------------------------------------------
#define BDST 132

__global__ __launch_bounds__(256)
void attn_f16(const unsigned short* __restrict__ qb,
              const unsigned short* __restrict__ kb,
              const unsigned short* __restrict__ vtg,   // V^T [b][feat][t], f16
              const unsigned short* __restrict__ pb,    // [2047][FEAT], f16
              const int* __restrict__ mask,
              const float* __restrict__ pbu, const float* __restrict__ pbv,
              float* __restrict__ xout)
{
    extern __shared__ unsigned short sm[];
    unsigned short* qu  = sm;                // 64*72
    unsigned short* qv  = qu  + 64 * 72;
    unsigned short* kt  = qv  + 64 * 72;
    unsigned short* vtT = kt  + 64 * 72;
    unsigned short* pt  = vtT + 64 * 72;     // 128*72
    unsigned short* ps  = pt  + 128 * 72;    // 64*72
    unsigned short* bdb = ps  + 64 * 72;     // 64*BDST
    f16* bdf = (f16*)bdb;
    f16* psf = (f16*)ps;

    const int tid = threadIdx.x;
    const int w = tid >> 6, lane = tid & 63, g = lane >> 4, c = lane & 15;
    const int t0 = blockIdx.x * 64;
    const int b  = blockIdx.y >> 3, h = blockIdx.y & 7;

    const unsigned short* qsrc = qb + ((size_t)b * T_SEQ) * FEAT + h * DKH;
    const unsigned short* ksrc = kb + ((size_t)b * T_SEQ) * FEAT + h * DKH;
    const unsigned short* vsrc = vtg + ((size_t)(b * FEAT + h * DKH)) * T_SEQ;
    const unsigned short* psrc = pb + h * DKH;

    // ---- stage qu = q+u, qv = q+v (f16, bias add in fp32)
#pragma unroll
    for (int q2 = 0; q2 < 2; ++q2) {
        const int id = tid + 256 * q2, row = id >> 3, chq = id & 7;
        const f16x8 q8 = *(const f16x8*)&qsrc[(size_t)(t0 + row) * FEAT + chq * 8];
        const float4 u0 = *(const float4*)&pbu[h * DKH + chq * 8];
        const float4 u1 = *(const float4*)&pbu[h * DKH + chq * 8 + 4];
        const float4 v0 = *(const float4*)&pbv[h * DKH + chq * 8];
        const float4 v1 = *(const float4*)&pbv[h * DKH + chq * 8 + 4];
        const float ub[8] = {u0.x, u0.y, u0.z, u0.w, u1.x, u1.y, u1.z, u1.w};
        const float vb[8] = {v0.x, v0.y, v0.z, v0.w, v1.x, v1.y, v1.z, v1.w};
        f16x8 ou, ov;
#pragma unroll
        for (int j = 0; j < 8; ++j) {
            const float f = (float)q8[j];
            ou[j] = (f16)(f + ub[j]);
            ov[j] = (f16)(f + vb[j]);
        }
        *(f16x8*)&qu[row * 72 + chq * 8] = ou;
        *(f16x8*)&qv[row * 72 + chq * 8] = ov;
    }

    f32x4 accO[4];
    float m_r[4], l_r[4];
#pragma unroll
    for (int n = 0; n < 4; ++n)
#pragma unroll
        for (int r = 0; r < 4; ++r) accO[n][r] = 0.f;
#pragma unroll
    for (int r = 0; r < 4; ++r) { m_r[r] = -3.0e38f; l_r[r] = 0.f; }

    for (int st = 0; st < 16; ++st) {
        const int s0 = st * 64;
        const int pbase = (T_SEQ - DKH) - t0 + s0;   // p row = pbase + (63 - ti + si)
        __syncthreads();   // A: prev-iter PV readers done
#pragma unroll
        for (int q2 = 0; q2 < 2; ++q2) {
            const int id = tid + 256 * q2, row = id >> 3, chq = id & 7;
            *(u16x8*)&kt[row * 72 + chq * 8] =
                *(const u16x8*)&ksrc[(size_t)(s0 + row) * FEAT + chq * 8];
            *(u16x8*)&vtT[row * 72 + chq * 8] =
                *(const u16x8*)&vsrc[(size_t)row * T_SEQ + s0 + chq * 8];
        }
#pragma unroll
        for (int q2 = 0; q2 < 4; ++q2) {
            const int id = tid + 256 * q2, prow = id >> 3, chq = id & 7;
            u16x8 p8;
            if (prow < 127)
                p8 = *(const u16x8*)&psrc[(size_t)(pbase + prow) * FEAT + chq * 8];
            else {
#pragma unroll
                for (int j = 0; j < 8; ++j) p8[j] = 0;
            }
            *(u16x8*)&pt[prow * 72 + chq * 8] = p8;
        }
        __syncthreads();   // B: tiles ready

        // ---- AC = (q+u) K^T
        f32x4 acS[4];
#pragma unroll
        for (int j = 0; j < 4; ++j)
#pragma unroll
            for (int r = 0; r < 4; ++r) acS[j][r] = 0.f;
        const f16x8 aq0 = *(const f16x8*)&qu[(16 * w + c) * 72 + 8 * g];
        const f16x8 aq1 = *(const f16x8*)&qu[(16 * w + c) * 72 + 32 + 8 * g];
#pragma unroll
        for (int j = 0; j < 4; ++j) {
            const f16x8 b0 = *(const f16x8*)&kt[(16 * j + c) * 72 + 8 * g];
            const f16x8 b1 = *(const f16x8*)&kt[(16 * j + c) * 72 + 32 + 8 * g];
            acS[j] = __builtin_amdgcn_mfma_f32_16x16x32_f16(aq0, b0, acS[j], 0, 0, 0);
            acS[j] = __builtin_amdgcn_mfma_f32_16x16x32_f16(aq1, b1, acS[j], 0, 0, 0);
        }

        // ---- BD = (q+v) P_window^T  (128 window rows)
        const f16x8 av0 = *(const f16x8*)&qv[(16 * w + c) * 72 + 8 * g];
        const f16x8 av1 = *(const f16x8*)&qv[(16 * w + c) * 72 + 32 + 8 * g];
#pragma unroll
        for (int jj = 0; jj < 8; ++jj) {
            f32x4 bda;
#pragma unroll
            for (int r = 0; r < 4; ++r) bda[r] = 0.f;
            const f16x8 b0 = *(const f16x8*)&pt[(16 * jj + c) * 72 + 8 * g];
            const f16x8 b1 = *(const f16x8*)&pt[(16 * jj + c) * 72 + 32 + 8 * g];
            bda = __builtin_amdgcn_mfma_f32_16x16x32_f16(av0, b0, bda, 0, 0, 0);
            bda = __builtin_amdgcn_mfma_f32_16x16x32_f16(av1, b1, bda, 0, 0, 0);
#pragma unroll
            for (int r = 0; r < 4; ++r)
                bdf[(16 * w + 4 * g + r) * BDST + 16 * jj + c] = (f16)bda[r];
        }
        __syncthreads();   // C: bd visible

        // ---- online softmax; rows ti = 16w+4g+r, cols si = 16j+c
        int mk[4];
#pragma unroll
        for (int j = 0; j < 4; ++j) mk[j] = mask[b * T_SEQ + s0 + 16 * j + c];
#pragma unroll
        for (int r = 0; r < 4; ++r) {
            const int ti = 16 * w + 4 * g + r;
            float sv[4];
#pragma unroll
            for (int j = 0; j < 4; ++j) {
                const float bdv = (float)bdf[ti * BDST + (63 - ti + 16 * j + c)];
                sv[j] = (mk[j] == 0) ? -1.0e30f : (acS[j][r] + bdv) * 0.125f;
            }
            float mx = fmaxf(fmaxf(sv[0], sv[1]), fmaxf(sv[2], sv[3]));
            mx = fmaxf(mx, __shfl_xor(mx, 1)); mx = fmaxf(mx, __shfl_xor(mx, 2));
            mx = fmaxf(mx, __shfl_xor(mx, 4)); mx = fmaxf(mx, __shfl_xor(mx, 8));
            const float mnew = fmaxf(m_r[r], mx);
            const float corr = __expf(m_r[r] - mnew);
            m_r[r] = mnew;
            float rs = 0.f;
#pragma unroll
            for (int j = 0; j < 4; ++j) {
                const float e = (mk[j] == 0) ? 0.f : __expf(sv[j] - mnew);
                rs += e;
                psf[ti * 72 + 16 * j + c] = (f16)e;
            }
            rs += __shfl_xor(rs, 1); rs += __shfl_xor(rs, 2);
            rs += __shfl_xor(rs, 4); rs += __shfl_xor(rs, 8);
            l_r[r] = l_r[r] * corr + rs;
#pragma unroll
            for (int n = 0; n < 4; ++n) accO[n][r] *= corr;
        }
        __syncthreads();   // D: P visible

        // ---- PV: O += P V
        const f16x8 pa0 = *(const f16x8*)&ps[(16 * w + c) * 72 + 8 * g];
        const f16x8 pa1 = *(const f16x8*)&ps[(16 * w + c) * 72 + 32 + 8 * g];
#pragma unroll
        for (int n = 0; n < 4; ++n) {
            const f16x8 b0 = *(const f16x8*)&vtT[(16 * n + c) * 72 + 8 * g];
            const f16x8 b1 = *(const f16x8*)&vtT[(16 * n + c) * 72 + 32 + 8 * g];
            accO[n] = __builtin_amdgcn_mfma_f32_16x16x32_f16(pa0, b0, accO[n], 0, 0, 0);
            accO[n] = __builtin_amdgcn_mfma_f32_16x16x32_f16(pa1, b1, accO[n], 0, 0, 0);
        }
    }

    // ---- epilogue: fp32 x
#pragma unroll
    for (int r = 0; r < 4; ++r) {
        const float inv = (l_r[r] > 0.f) ? 1.0f / l_r[r] : 0.f;
        const int t = t0 + 16 * w + 4 * g + r;
#pragma unroll
        for (int n = 0; n < 4; ++n)
            xout[((size_t)(b * T_SEQ + t)) * FEAT + h * DKH + 16 * n + c] = accO[n][r] * inv;
    }
}

// ---------------------------------------------------------------------------
extern "C" void kernel_launch(void* const* d_in, const int* in_sizes, int n_in,
                              void* d_out, int out_size, void* d_ws, size_t ws_size,
                              hipStream_t stream)
{
    (void)in_sizes; (void)n_in; (void)out_size; (void)ws_size;
    const float* query   = (const float*)d_in[0];
    const float* key_in  = (const float*)d_in[1];
    const float* value   = (const float*)d_in[2];
    const float* pos_emb = (const float*)d_in[3];
    const int*   mask    = (const int*)  d_in[4];
    const float* Wq = (const float*)d_in[5];
    const float* bq = (const float*)d_in[6];
    const float* Wk = (const float*)d_in[7];
    const float* bk = (const float*)d_in[8];
    const float* Wv = (const float*)d_in[9];
    const float* bv = (const float*)d_in[10];
    const float* Wo = (const float*)d_in[11];
    const float* bo = (const float*)d_in[12];
    const float* Wp = (const float*)d_in[13];
    const float* pbu = (const float*)d_in[14];
    const float* pbv = (const float*)d_in[15];
    float* out = (float*)d_out;

    const size_t NTOK = (size_t)8 * T_SEQ;       // 8192
    char* wsp = (char*)d_ws;
    size_t off = 0;
    auto alloc = [&](size_t bytes) { char* p = wsp + off; off += (bytes + 255) & ~255ull; return p; };

    unsigned short* qbf = (unsigned short*)alloc(NTOK * FEAT * 2);        // f16
    unsigned short* kbf = (unsigned short*)alloc(NTOK * FEAT * 2);        // f16
    unsigned short* vTb = (unsigned short*)alloc(NTOK * FEAT * 2);        // f16 [b][feat][t]
    unsigned short* pbf = (unsigned short*)alloc((size_t)2047 * FEAT * 2);// f16
    float*          xbf = (float*)alloc(NTOK * FEAT * 4);                 // fp32
    unsigned short* wh[5]; unsigned short* wl[5];
    for (int i = 0; i < 5; ++i) {
        wh[i] = (unsigned short*)alloc((size_t)FEAT * FEAT * 2);
        wl[i] = (unsigned short*)alloc((size_t)FEAT * FEAT * 2);
    }

    WSplit sp;
    const float* wsrc[5] = {Wq, Wk, Wv, Wp, Wo};
    for (int i = 0; i < 5; ++i) { sp.src[i] = wsrc[i]; sp.hi[i] = wh[i]; sp.lo[i] = wl[i]; }
    split_weights<<<dim3(64, 5), 256, 0, stream>>>(sp);

    gemm_split<1><<<dim3(64, 4), 256, 0, stream>>>(query,  wh[0], wl[0], bq, qbf, 8192, FEAT, FEAT);
    gemm_split<1><<<dim3(64, 4), 256, 0, stream>>>(key_in, wh[1], wl[1], bk, kbf, 8192, FEAT, FEAT);
    gemm_split<2><<<dim3(64, 4), 256, 0, stream>>>(value,  wh[2], wl[2], bv, vTb, 8192, FEAT, FEAT);
    gemm_split<1><<<dim3(16, 4), 256, 0, stream>>>(pos_emb, wh[3], wl[3], nullptr, pbf, 2047, FEAT, FEAT);

    const int lds_bytes = (64 * 72 * 4 + 128 * 72 + 64 * 72 + 64 * BDST) * 2;  // 81408
    hipFuncSetAttribute((const void*)attn_f16,
                        hipFuncAttributeMaxDynamicSharedMemorySize, lds_bytes);
    attn_f16<<<dim3(16, 64), 256, lds_bytes, stream>>>(qbf, kbf, vTb, pbf,
                                                       mask, pbu, pbv, xbf);

    gemm_split<0><<<dim3(64, 4), 256, 0, stream>>>(xbf, wh[4], wl[4], bo, out, 8192, FEAT, FEAT);
}